// Round 1
// baseline (214.230 us; speedup 1.0000x reference)
//
#include <hip/hip_runtime.h>

#define NPTS 16384
#define MPB  8
#define NTHR 256
#define WS_NEEDED 401408u

typedef __attribute__((ext_vector_type(8))) short bf16x8;
typedef __attribute__((ext_vector_type(4))) float f32x4;

__device__ __forceinline__ unsigned short f2bf(float x) {
    unsigned u = __float_as_uint(x);
    return (unsigned short)((u + 0x7FFFu + ((u >> 16) & 1u)) >> 16);
}
__device__ __forceinline__ float bf2f(unsigned short h) {
    return __uint_as_float(((unsigned)h) << 16);
}
__device__ __forceinline__ float elu_f(float x) {
    return x > 0.f ? x : (__expf(x) - 1.f);
}

// Gather one 16x16x32 B-fragment directly from a row-major fp32 matrix W[K][N].
// lane l holds B[kt*32 + (l>>4)*8 + j][nt*16 + (l&15)], j=0..7
__device__ __forceinline__ bf16x8 load_bfrag(const float* __restrict__ W, int N,
                                             int kt, int nt, int lane) {
    int k0  = kt * 32 + ((lane >> 4) << 3);
    int col = nt * 16 + (lane & 15);
    const float* s = W + k0 * N + col;
    bf16x8 r;
#pragma unroll
    for (int j = 0; j < 8; j++) r[j] = (short)f2bf(s[j * N]);
    return r;
}

// ---------------- prep: pack w2 / wx1 / wx2 / wpw into bf16 B-fragments ----
// frag order: w2 [kt*4+nt] (8), wx1 [kt*16+nt] (128), wx2 (128), wpw [kt*8+nt] (128)
// dst layout: [frag][lane][8] bf16  => 392 frags * 1KB = 392KB
__global__ void pack_weights(const float* __restrict__ w2,
                             const float* __restrict__ wx1,
                             const float* __restrict__ wx2,
                             const float* __restrict__ wpw,
                             unsigned short* __restrict__ dst) {
    int gid  = blockIdx.x * 256 + threadIdx.x;   // 98*256 = 25088 = 392*64
    int frag = gid >> 6, lane = gid & 63;
    const float* src; int N, fl;
    if      (frag <   8) { src = w2;  N =  64; fl = frag;       }
    else if (frag < 136) { src = wx1; N = 256; fl = frag - 8;   }
    else if (frag < 264) { src = wx2; N = 256; fl = frag - 136; }
    else                 { src = wpw; N = 128; fl = frag - 264; }
    int NT  = N >> 4;
    int kt  = fl / NT, nt = fl - kt * NT;
    int k0  = kt * 32 + (lane >> 4) * 8;
    int col = nt * 16 + (lane & 15);
    const float* s = src + k0 * N + col;
    unsigned v[4];
#pragma unroll
    for (int u = 0; u < 4; u++) {
        unsigned lo = f2bf(s[(2 * u) * N]);
        unsigned hi = f2bf(s[(2 * u + 1) * N]);
        v[u] = lo | (hi << 16);
    }
    *(uint4*)&dst[gid * 8] = make_uint4(v[0], v[1], v[2], v[3]);
}

// ---------------- main fused kernel -----------------------------------------
// MPB=8 tile: LDS = 36352 B -> 4 blocks/CU (was 62976 B -> 2 blocks/CU).
// Layout:
//   0     s_ptsl [8][48]  f32   1536
//   1536  s_h2   [128][64] u16 16384   (alive B..F)
//   17920 overlay region  18432:
//         s_h1 [128][72] u16 18432  (B only)
//         s_x0 [8][264]  u16  4224  (C->D)   @17920
//         s_x1 [8][264]  u16  4224  (D->E)   @22144
//         s_x2 [8][264]  f32  8448  (E->F)   @26368  (f32: no unpack in F)
//         s_dw [8][520]  u16  8320  (F->G)   @17920
// 16-row MFMAs run with M=8: A-reads use (lane&7) row duplication; C-row
// stores masked to lane<32 (rows 0..7).
template <bool PACKED>
__global__ __launch_bounds__(NTHR, 4)
void xconv_main(const float* __restrict__ rep_pt, const float* __restrict__ pts,
                const float* __restrict__ fts,
                const float* __restrict__ w1,  const float* __restrict__ b1,
                const float* __restrict__ w2,  const float* __restrict__ b2,
                const float* __restrict__ wc1, const float* __restrict__ bc1,
                const float* __restrict__ wx1, const float* __restrict__ bx1,
                const float* __restrict__ wx2, const float* __restrict__ bx2,
                const float* __restrict__ wdw, const float* __restrict__ bdw,
                const float* __restrict__ wpw, const float* __restrict__ bpw,
                const float* __restrict__ bn_gamma, const float* __restrict__ bn_beta,
                const float* __restrict__ bn_mean,  const float* __restrict__ bn_var,
                const unsigned short* __restrict__ wpack,
                float* __restrict__ out) {
    __shared__ __align__(16) char smem[36352];
    float*          s_ptsl = (float*)smem;                          // [8][48]
    unsigned short* s_h2   = (unsigned short*)(smem + 1536);        // [128][64]
    unsigned short* s_h1   = (unsigned short*)(smem + 17920);       // [128][72]
    unsigned short* s_x0   = (unsigned short*)(smem + 17920);       // [8][264]
    unsigned short* s_x1   = (unsigned short*)(smem + 22144);       // [8][264]
    float*          s_x2   = (float*)(smem + 26368);                // [8][264]
    unsigned short* s_dw   = (unsigned short*)(smem + 17920);       // [8][520]

    const int t    = threadIdx.x;
    const int lane = t & 63;
    const int w    = t >> 6;
    const int gp0  = blockIdx.x * MPB;

    // ---- Phase A: pts_local -> LDS ----
    for (int idx = t; idx < MPB * 48; idx += NTHR) {
        int m = idx / 48, r = idx - m * 48;
        int k = r / 3,    d = r - k * 3;
        int gp = gp0 + m;
        s_ptsl[idx] = pts[(gp * 16 + k) * 3 + d] - rep_pt[gp * 3 + d];
    }
    __syncthreads();

    // ---- Phase B: h1 (VALU, K=3) then h2 = elu(h1@w2+b2) via MFMA, 1 round ----
    {   // h1: 2 threads per row, 32 channels each; 256 threads -> 128 rows
        int lr  = t >> 1;                 // row = m*16+k, 0..127
        int m = lr >> 4, k = lr & 15;
        float p0 = s_ptsl[m * 48 + k * 3 + 0];
        float p1 = s_ptsl[m * 48 + k * 3 + 1];
        float p2 = s_ptsl[m * 48 + k * 3 + 2];
        int cb = (t & 1) * 32;
#pragma unroll
        for (int cc = 0; cc < 4; cc++) {
            unsigned v[4];
#pragma unroll
            for (int u = 0; u < 4; u++) {
                int c0 = cb + cc * 8 + u * 2;
                float a  = fmaf(p0, w1[c0],       fmaf(p1, w1[64 + c0],     fmaf(p2, w1[128 + c0],     b1[c0])));
                float bb = fmaf(p0, w1[c0 + 1],   fmaf(p1, w1[64 + c0 + 1], fmaf(p2, w1[128 + c0 + 1], b1[c0 + 1])));
                v[u] = (unsigned)f2bf(elu_f(a)) | ((unsigned)f2bf(elu_f(bb)) << 16);
            }
            *(uint4*)&s_h1[lr * 72 + cb + cc * 8] = make_uint4(v[0], v[1], v[2], v[3]);
        }
    }
    __syncthreads();
    {   // h2 MFMA: 8 row-tiles of 16, K=64 (2 kt), N=64 (4 nt)
        const bf16x8* wp = (const bf16x8*)wpack;   // w2 frags at base 0
        bf16x8 Bf[8];
#pragma unroll
        for (int f = 0; f < 8; f++) {
            if (PACKED) Bf[f] = wp[f * 64 + lane];
            else        Bf[f] = load_bfrag(w2, 64, f >> 2, f & 3, lane);
        }
        float bias[4];
#pragma unroll
        for (int nt = 0; nt < 4; nt++) bias[nt] = b2[nt * 16 + (lane & 15)];
#pragma unroll
        for (int i = 0; i < 2; i++) {
            int rtl = w * 2 + i;              // 0..7
            int g0  = rtl * 16;
            bf16x8 a0 = *(const bf16x8*)&s_h1[(rtl * 16 + (lane & 15)) * 72 + 0  + (lane >> 4) * 8];
            bf16x8 a1 = *(const bf16x8*)&s_h1[(rtl * 16 + (lane & 15)) * 72 + 32 + (lane >> 4) * 8];
#pragma unroll
            for (int nt = 0; nt < 4; nt++) {
                f32x4 acc = {bias[nt], bias[nt], bias[nt], bias[nt]};
                acc = __builtin_amdgcn_mfma_f32_16x16x32_bf16(a0, Bf[0 * 4 + nt], acc, 0, 0, 0);
                acc = __builtin_amdgcn_mfma_f32_16x16x32_bf16(a1, Bf[1 * 4 + nt], acc, 0, 0, 0);
#pragma unroll
                for (int r = 0; r < 4; r++) {
                    int krow = (lane >> 4) * 4 + r;
                    s_h2[(g0 + krow) * 64 + nt * 16 + (lane & 15)] = f2bf(elu_f(acc[r]));
                }
            }
        }
    }
    __syncthreads();

    // ---- Phase C: X0 = elu(ptsl einsum wc1 + bc1) (VALU), write bf16 A-layout ----
    {
        float wreg[48];                       // wc1[o][d][k] -> wreg[d*16+k]
#pragma unroll
        for (int q = 0; q < 12; q++) {
            float4 wv = *(const float4*)&wc1[t * 48 + q * 4];
            wreg[q * 4 + 0] = wv.x; wreg[q * 4 + 1] = wv.y;
            wreg[q * 4 + 2] = wv.z; wreg[q * 4 + 3] = wv.w;
        }
        float bo = bc1[t];
#pragma unroll 1
        for (int m = 0; m < MPB; m++) {
            float acc = bo;
#pragma unroll
            for (int q = 0; q < 12; q++) {
                float4 pv = *(const float4*)&s_ptsl[m * 48 + q * 4];   // flat f = k*3+d
                acc = fmaf(pv.x, wreg[((q * 4 + 0) % 3) * 16 + (q * 4 + 0) / 3], acc);
                acc = fmaf(pv.y, wreg[((q * 4 + 1) % 3) * 16 + (q * 4 + 1) / 3], acc);
                acc = fmaf(pv.z, wreg[((q * 4 + 2) % 3) * 16 + (q * 4 + 2) / 3], acc);
                acc = fmaf(pv.w, wreg[((q * 4 + 3) % 3) * 16 + (q * 4 + 3) / 3], acc);
            }
            s_x0[m * 264 + t] = f2bf(elu_f(acc));
        }
    }
    __syncthreads();

    // ---- Phase D: X1 = elu(X0 @ wx1 + bx1), MFMA, M=8(dup to 16),N=256,K=256 ----
    {
        const bf16x8* wp = (const bf16x8*)wpack + 512;  // wx1
        f32x4 acc[4];
#pragma unroll
        for (int q = 0; q < 4; q++) {
            float bv = bx1[(w * 4 + q) * 16 + (lane & 15)];
            acc[q] = (f32x4){bv, bv, bv, bv};
        }
#pragma unroll
        for (int kt = 0; kt < 8; kt++) {
            bf16x8 a = *(const bf16x8*)&s_x0[(lane & 7) * 264 + kt * 32 + (lane >> 4) * 8];
#pragma unroll
            for (int q = 0; q < 4; q++) {
                int nt = w * 4 + q;
                bf16x8 b;
                if (PACKED) b = wp[(kt * 16 + nt) * 64 + lane];
                else        b = load_bfrag(wx1, 256, kt, nt, lane);
                acc[q] = __builtin_amdgcn_mfma_f32_16x16x32_bf16(a, b, acc[q], 0, 0, 0);
            }
        }
        if (lane < 32) {
#pragma unroll
            for (int q = 0; q < 4; q++) {
                int nt = w * 4 + q;
#pragma unroll
                for (int r = 0; r < 4; r++) {
                    int m = (lane >> 4) * 4 + r;      // 0..7
                    s_x1[m * 264 + nt * 16 + (lane & 15)] = f2bf(elu_f(acc[q][r]));
                }
            }
        }
    }
    __syncthreads();

    // ---- Phase E: X2 = X1 @ wx2 + bx2 (no act), MFMA; store f32 ----
    {
        const bf16x8* wp = (const bf16x8*)wpack + 8704;  // wx2
        f32x4 acc[4];
#pragma unroll
        for (int q = 0; q < 4; q++) {
            float bv = bx2[(w * 4 + q) * 16 + (lane & 15)];
            acc[q] = (f32x4){bv, bv, bv, bv};
        }
#pragma unroll
        for (int kt = 0; kt < 8; kt++) {
            bf16x8 a = *(const bf16x8*)&s_x1[(lane & 7) * 264 + kt * 32 + (lane >> 4) * 8];
#pragma unroll
            for (int q = 0; q < 4; q++) {
                int nt = w * 4 + q;
                bf16x8 b;
                if (PACKED) b = wp[(kt * 16 + nt) * 64 + lane];
                else        b = load_bfrag(wx2, 256, kt, nt, lane);
                acc[q] = __builtin_amdgcn_mfma_f32_16x16x32_bf16(a, b, acc[q], 0, 0, 0);
            }
        }
        if (lane < 32) {
#pragma unroll
            for (int q = 0; q < 4; q++) {
                int nt = w * 4 + q;
#pragma unroll
                for (int r = 0; r < 4; r++) {
                    int m = (lane >> 4) * 4 + r;      // 0..7
                    s_x2[m * 264 + nt * 16 + (lane & 15)] = acc[q][r];
                }
            }
        }
    }
    __syncthreads();

    // ---- Phase F: fts_X = X2 @ fts_cat  +  depthwise (VALU) ----
    {
        const int c  = t & 127;
        const int mg = t >> 7;
        float wd[64];
#pragma unroll
        for (int q = 0; q < 16; q++) {
            float4 v = *(const float4*)&wdw[c * 64 + q * 4];
            wd[q * 4 + 0] = v.x; wd[q * 4 + 1] = v.y;
            wd[q * 4 + 2] = v.z; wd[q * 4 + 3] = v.w;
        }
        float bd[4];
#pragma unroll
        for (int d = 0; d < 4; d++) bd[d] = bdw[c * 4 + d];
#pragma unroll 1
        for (int ml = 0; ml < 4; ml++) {
            int m  = mg * 4 + ml;                      // 0..7
            int gp = gp0 + m;
            float fc[16];
            if (c < 64) {
#pragma unroll
                for (int j = 0; j < 16; j++) fc[j] = bf2f(s_h2[(m * 16 + j) * 64 + c]);
            } else {
#pragma unroll
                for (int j = 0; j < 16; j++) fc[j] = fts[(gp * 16 + j) * 64 + (c - 64)];
            }
            float fXr[16];
#pragma unroll
            for (int i = 0; i < 16; i++) {
                float a = 0.f;
#pragma unroll
                for (int jj = 0; jj < 4; jj++) {
                    float4 xv = *(const float4*)&s_x2[m * 264 + i * 16 + jj * 4];
                    a = fmaf(xv.x, fc[jj * 4 + 0], a);
                    a = fmaf(xv.y, fc[jj * 4 + 1], a);
                    a = fmaf(xv.z, fc[jj * 4 + 2], a);
                    a = fmaf(xv.w, fc[jj * 4 + 3], a);
                }
                fXr[i] = a;
            }
            ushort4 dv;
            {
                float o[4];
#pragma unroll
                for (int d = 0; d < 4; d++) {
                    float a = bd[d];
#pragma unroll
                    for (int k = 0; k < 16; k++) a = fmaf(fXr[k], wd[d * 16 + k], a);
                    o[d] = a;
                }
                dv.x = f2bf(o[0]); dv.y = f2bf(o[1]); dv.z = f2bf(o[2]); dv.w = f2bf(o[3]);
            }
            *(ushort4*)&s_dw[m * 520 + c * 4] = dv;
        }
    }
    __syncthreads();

    // ---- Phase G: y = BN(elu(dw @ wpw + bpw)), MFMA M=8(dup),N=128,K=512 ----
    {
        const bf16x8* wp = (const bf16x8*)wpack + 16896;  // wpw
        f32x4 acc[2];
#pragma unroll
        for (int q = 0; q < 2; q++) {
            float bv = bpw[(w * 2 + q) * 16 + (lane & 15)];
            acc[q] = (f32x4){bv, bv, bv, bv};
        }
#pragma unroll
        for (int kt = 0; kt < 16; kt++) {
            bf16x8 a = *(const bf16x8*)&s_dw[(lane & 7) * 520 + kt * 32 + (lane >> 4) * 8];
#pragma unroll
            for (int q = 0; q < 2; q++) {
                int nt = w * 2 + q;
                bf16x8 b;
                if (PACKED) b = wp[(kt * 8 + nt) * 64 + lane];
                else        b = load_bfrag(wpw, 128, kt, nt, lane);
                acc[q] = __builtin_amdgcn_mfma_f32_16x16x32_bf16(a, b, acc[q], 0, 0, 0);
            }
        }
        if (lane < 32) {
#pragma unroll
            for (int q = 0; q < 2; q++) {
                int co = (w * 2 + q) * 16 + (lane & 15);
                float scale = bn_gamma[co] * rsqrtf(bn_var[co] + 1e-5f);
                float shift = bn_beta[co] - bn_mean[co] * scale;
#pragma unroll
                for (int r = 0; r < 4; r++) {
                    int m = (lane >> 4) * 4 + r;      // 0..7
                    out[(gp0 + m) * 128 + co] = fmaf(elu_f(acc[q][r]), scale, shift);
                }
            }
        }
    }
}

extern "C" void kernel_launch(void* const* d_in, const int* in_sizes, int n_in,
                              void* d_out, int out_size, void* d_ws, size_t ws_size,
                              hipStream_t stream) {
    const float* rep_pt   = (const float*)d_in[0];
    const float* pts      = (const float*)d_in[1];
    const float* fts      = (const float*)d_in[2];
    const float* w1       = (const float*)d_in[3];
    const float* b1       = (const float*)d_in[4];
    const float* w2       = (const float*)d_in[5];
    const float* b2       = (const float*)d_in[6];
    const float* wc1      = (const float*)d_in[7];
    const float* bc1      = (const float*)d_in[8];
    const float* wx1      = (const float*)d_in[9];
    const float* bx1      = (const float*)d_in[10];
    const float* wx2      = (const float*)d_in[11];
    const float* bx2      = (const float*)d_in[12];
    const float* wdw      = (const float*)d_in[13];
    const float* bdw      = (const float*)d_in[14];
    const float* wpw      = (const float*)d_in[15];
    const float* bpw      = (const float*)d_in[16];
    const float* bn_gamma = (const float*)d_in[17];
    const float* bn_beta  = (const float*)d_in[18];
    const float* bn_mean  = (const float*)d_in[19];
    const float* bn_var   = (const float*)d_in[20];
    float* out = (float*)d_out;

    const bool packed = (d_ws != nullptr) && (ws_size >= (size_t)WS_NEEDED);
    unsigned short* wpack = (unsigned short*)d_ws;

    if (packed) {
        pack_weights<<<98, 256, 0, stream>>>(w2, wx1, wx2, wpw, wpack);
        xconv_main<true><<<NPTS / MPB, NTHR, 0, stream>>>(
            rep_pt, pts, fts, w1, b1, w2, b2, wc1, bc1, wx1, bx1, wx2, bx2,
            wdw, bdw, wpw, bpw, bn_gamma, bn_beta, bn_mean, bn_var, wpack, out);
    } else {
        xconv_main<false><<<NPTS / MPB, NTHR, 0, stream>>>(
            rep_pt, pts, fts, w1, b1, w2, b2, wc1, bc1, wx1, bx1, wx2, bx2,
            wdw, bdw, wpw, bpw, bn_gamma, bn_beta, bn_mean, bn_var, (const unsigned short*)nullptr, out);
    }
}

// Round 2
// 198.680 us; speedup vs baseline: 1.0783x; 1.0783x over previous
//
#include <hip/hip_runtime.h>

#define NPTS 16384
#define MPB  16
#define NTHR 256
#define WS_NEEDED 401408u

typedef __attribute__((ext_vector_type(8))) short bf16x8;
typedef __attribute__((ext_vector_type(4))) float f32x4;

__device__ __forceinline__ unsigned short f2bf(float x) {
    unsigned u = __float_as_uint(x);
    return (unsigned short)((u + 0x7FFFu + ((u >> 16) & 1u)) >> 16);
}
__device__ __forceinline__ unsigned pk2(float a, float b) {
    return (unsigned)f2bf(a) | ((unsigned)f2bf(b) << 16);
}
__device__ __forceinline__ float bf2f(unsigned short h) {
    return __uint_as_float(((unsigned)h) << 16);
}
__device__ __forceinline__ float elu_f(float x) {
    return x > 0.f ? x : (__expf(x) - 1.f);
}

// Gather one 16x16x32 B-fragment directly from a row-major fp32 matrix W[K][N].
__device__ __forceinline__ bf16x8 load_bfrag(const float* __restrict__ W, int N,
                                             int kt, int nt, int lane) {
    int k0  = kt * 32 + ((lane >> 4) << 3);
    int col = nt * 16 + (lane & 15);
    const float* s = W + k0 * N + col;
    bf16x8 r;
#pragma unroll
    for (int j = 0; j < 8; j++) r[j] = (short)f2bf(s[j * N]);
    return r;
}

// ---------------- prep: pack w2 / wx1 / wx2 / wpw into bf16 B-fragments ----
__global__ void pack_weights(const float* __restrict__ w2,
                             const float* __restrict__ wx1,
                             const float* __restrict__ wx2,
                             const float* __restrict__ wpw,
                             unsigned short* __restrict__ dst) {
    int gid  = blockIdx.x * 256 + threadIdx.x;   // 98*256 = 25088 = 392*64
    int frag = gid >> 6, lane = gid & 63;
    const float* src; int N, fl;
    if      (frag <   8) { src = w2;  N =  64; fl = frag;       }
    else if (frag < 136) { src = wx1; N = 256; fl = frag - 8;   }
    else if (frag < 264) { src = wx2; N = 256; fl = frag - 136; }
    else                 { src = wpw; N = 128; fl = frag - 264; }
    int NT  = N >> 4;
    int kt  = fl / NT, nt = fl - kt * NT;
    int k0  = kt * 32 + (lane >> 4) * 8;
    int col = nt * 16 + (lane & 15);
    const float* s = src + k0 * N + col;
    unsigned v[4];
#pragma unroll
    for (int u = 0; u < 4; u++) {
        unsigned lo = f2bf(s[(2 * u) * N]);
        unsigned hi = f2bf(s[(2 * u + 1) * N]);
        v[u] = lo | (hi << 16);
    }
    *(uint4*)&dst[gid * 8] = make_uint4(v[0], v[1], v[2], v[3]);
}

// ---------------- main fused kernel -----------------------------------------
// MPB=16. LDS map (60928 B total -> 2 blocks/CU):
//   0     s_ptsl [16][48] f32                 3072
//   3072  s_h2f  [16 m][4 nt][32 lane][8] u16 32768  (B-fragment layout, B..F)
//   35840 overlay region 25088:
//         s_h1  [128][72] u16 18432   (B only)
//         s_x0  [16][264] u16  8448   (C->D)  @35840
//         s_x2f [16][32][8] u16 8192  (E->F)  @35840 (A-frag layout)
//         s_x1  [16][264] u16  8448   (D->E)  @44288
//         s_dw  [16][520] u16 16640   (F->G)  @44288
// Phase F: fts_X via zero-padded 16x16x32 MFMA (K=16 in lanes 0..31),
// depthwise partials + shfl_xor(16/32) butterfly.
template <bool PACKED>
__global__ __launch_bounds__(NTHR, 2)
void xconv_main(const float* __restrict__ rep_pt, const float* __restrict__ pts,
                const float* __restrict__ fts,
                const float* __restrict__ w1,  const float* __restrict__ b1,
                const float* __restrict__ w2,  const float* __restrict__ b2,
                const float* __restrict__ wc1, const float* __restrict__ bc1,
                const float* __restrict__ wx1, const float* __restrict__ bx1,
                const float* __restrict__ wx2, const float* __restrict__ bx2,
                const float* __restrict__ wdw, const float* __restrict__ bdw,
                const float* __restrict__ wpw, const float* __restrict__ bpw,
                const float* __restrict__ bn_gamma, const float* __restrict__ bn_beta,
                const float* __restrict__ bn_mean,  const float* __restrict__ bn_var,
                const unsigned short* __restrict__ wpack,
                float* __restrict__ out) {
    __shared__ __align__(16) char smem[60928];
    float*          s_ptsl = (float*)smem;                          // [16][48]
    unsigned short* s_h2f  = (unsigned short*)(smem + 3072);        // [16][4][32][8]
    unsigned short* s_h1   = (unsigned short*)(smem + 35840);       // [128][72]
    unsigned short* s_x0   = (unsigned short*)(smem + 35840);       // [16][264]
    unsigned short* s_x2f  = (unsigned short*)(smem + 35840);       // [16][32][8]
    unsigned short* s_x1   = (unsigned short*)(smem + 44288);       // [16][264]
    unsigned short* s_dw   = (unsigned short*)(smem + 44288);       // [16][520]

    const int t    = threadIdx.x;
    const int lane = t & 63;
    const int w    = t >> 6;
    const int cl   = lane & 15;
    const int hh   = lane >> 4;
    const int gp0  = blockIdx.x * MPB;

    // ---- Phase A: pts_local -> LDS ----
    for (int idx = t; idx < MPB * 48; idx += NTHR) {
        int m = idx / 48, r = idx - m * 48;
        int k = r / 3,    d = r - k * 3;
        int gp = gp0 + m;
        s_ptsl[idx] = pts[(gp * 16 + k) * 3 + d] - rep_pt[gp * 3 + d];
    }
    __syncthreads();

    // ---- Phase B: h1 (VALU, K=3) then h2 = elu(h1@w2+b2) via MFMA, 2 rounds ----
    // h2 stored in B-fragment layout s_h2f for Phase F.
    {
        const bf16x8* wp = (const bf16x8*)wpack;   // w2 frags at base 0
        bf16x8 Bf[8];
#pragma unroll
        for (int f = 0; f < 8; f++) {
            if (PACKED) Bf[f] = wp[f * 64 + lane];
            else        Bf[f] = load_bfrag(w2, 64, f >> 2, f & 3, lane);
        }
        float bias[4];
#pragma unroll
        for (int nt = 0; nt < 4; nt++) bias[nt] = b2[nt * 16 + cl];

        for (int R = 0; R < 2; R++) {
            {   // h1: 2 threads per row, 32 channels each
                int lr  = t >> 1;
                int row = 128 * R + lr;           // global row = m*16+k
                int m = row >> 4, k = row & 15;
                float p0 = s_ptsl[m * 48 + k * 3 + 0];
                float p1 = s_ptsl[m * 48 + k * 3 + 1];
                float p2 = s_ptsl[m * 48 + k * 3 + 2];
                int cb = (t & 1) * 32;
#pragma unroll
                for (int cc = 0; cc < 4; cc++) {
                    unsigned v[4];
#pragma unroll
                    for (int u = 0; u < 4; u++) {
                        int c0 = cb + cc * 8 + u * 2;
                        float a  = fmaf(p0, w1[c0],     fmaf(p1, w1[64 + c0],     fmaf(p2, w1[128 + c0],     b1[c0])));
                        float bb = fmaf(p0, w1[c0 + 1], fmaf(p1, w1[64 + c0 + 1], fmaf(p2, w1[128 + c0 + 1], b1[c0 + 1])));
                        v[u] = pk2(elu_f(a), elu_f(bb));
                    }
                    *(uint4*)&s_h1[lr * 72 + cb + cc * 8] = make_uint4(v[0], v[1], v[2], v[3]);
                }
            }
            __syncthreads();
            {   // h2 MFMA: 8 row-tiles of 16, K=64 (2 kt), N=64 (4 nt)
#pragma unroll
                for (int i = 0; i < 2; i++) {
                    int rtl = w * 2 + i;
                    int m   = 8 * R + rtl;        // point index 0..15
                    bf16x8 a0 = *(const bf16x8*)&s_h1[(rtl * 16 + cl) * 72 + 0  + hh * 8];
                    bf16x8 a1 = *(const bf16x8*)&s_h1[(rtl * 16 + cl) * 72 + 32 + hh * 8];
#pragma unroll
                    for (int nt = 0; nt < 4; nt++) {
                        f32x4 acc = {bias[nt], bias[nt], bias[nt], bias[nt]};
                        acc = __builtin_amdgcn_mfma_f32_16x16x32_bf16(a0, Bf[0 * 4 + nt], acc, 0, 0, 0);
                        acc = __builtin_amdgcn_mfma_f32_16x16x32_bf16(a1, Bf[1 * 4 + nt], acc, 0, 0, 0);
                        // scatter to B-frag layout: k = 4*hh + r, lane' = (k>>3)*16+cl, j = k&7
                        unsigned lo = pk2(elu_f(acc[0]), elu_f(acc[1]));
                        unsigned hi = pk2(elu_f(acc[2]), elu_f(acc[3]));
                        unsigned short* dp = &s_h2f[(((m * 4 + nt) * 32) + (hh >> 1) * 16 + cl) * 8 + (hh & 1) * 4];
                        *(uint2*)dp = make_uint2(lo, hi);
                    }
                }
            }
            __syncthreads();
        }
    }

    // ---- Phase C: X0 = elu(ptsl einsum wc1 + bc1) (VALU), write bf16 A-layout ----
    {
        float wreg[48];                       // wc1[o][d][k] -> wreg[d*16+k]
#pragma unroll
        for (int q = 0; q < 12; q++) {
            float4 wv = *(const float4*)&wc1[t * 48 + q * 4];
            wreg[q * 4 + 0] = wv.x; wreg[q * 4 + 1] = wv.y;
            wreg[q * 4 + 2] = wv.z; wreg[q * 4 + 3] = wv.w;
        }
        float bo = bc1[t];
#pragma unroll 1
        for (int m = 0; m < MPB; m++) {
            float acc = bo;
#pragma unroll
            for (int q = 0; q < 12; q++) {
                float4 pv = *(const float4*)&s_ptsl[m * 48 + q * 4];   // flat f = k*3+d
                acc = fmaf(pv.x, wreg[((q * 4 + 0) % 3) * 16 + (q * 4 + 0) / 3], acc);
                acc = fmaf(pv.y, wreg[((q * 4 + 1) % 3) * 16 + (q * 4 + 1) / 3], acc);
                acc = fmaf(pv.z, wreg[((q * 4 + 2) % 3) * 16 + (q * 4 + 2) / 3], acc);
                acc = fmaf(pv.w, wreg[((q * 4 + 3) % 3) * 16 + (q * 4 + 3) / 3], acc);
            }
            s_x0[m * 264 + t] = f2bf(elu_f(acc));
        }
    }
    __syncthreads();

    // ---- Phase D: X1 = elu(X0 @ wx1 + bx1), MFMA, M=16,N=256,K=256 ----
    {
        const bf16x8* wp = (const bf16x8*)wpack + 512;  // wx1
        f32x4 acc[4];
#pragma unroll
        for (int q = 0; q < 4; q++) {
            float bv = bx1[(w * 4 + q) * 16 + cl];
            acc[q] = (f32x4){bv, bv, bv, bv};
        }
#pragma unroll
        for (int kt = 0; kt < 8; kt++) {
            bf16x8 a = *(const bf16x8*)&s_x0[cl * 264 + kt * 32 + hh * 8];
#pragma unroll
            for (int q = 0; q < 4; q++) {
                int nt = w * 4 + q;
                bf16x8 b;
                if (PACKED) b = wp[(kt * 16 + nt) * 64 + lane];
                else        b = load_bfrag(wx1, 256, kt, nt, lane);
                acc[q] = __builtin_amdgcn_mfma_f32_16x16x32_bf16(a, b, acc[q], 0, 0, 0);
            }
        }
#pragma unroll
        for (int q = 0; q < 4; q++) {
            int nt = w * 4 + q;
#pragma unroll
            for (int r = 0; r < 4; r++) {
                int m = hh * 4 + r;
                s_x1[m * 264 + nt * 16 + cl] = f2bf(elu_f(acc[q][r]));
            }
        }
    }
    __syncthreads();

    // ---- Phase E: X2 = X1 @ wx2 + bx2 (no act), MFMA; scatter to A-frag layout ----
    {
        const bf16x8* wp = (const bf16x8*)wpack + 8704;  // wx2
        f32x4 acc[4];
#pragma unroll
        for (int q = 0; q < 4; q++) {
            float bv = bx2[(w * 4 + q) * 16 + cl];
            acc[q] = (f32x4){bv, bv, bv, bv};
        }
#pragma unroll
        for (int kt = 0; kt < 8; kt++) {
            bf16x8 a = *(const bf16x8*)&s_x1[cl * 264 + kt * 32 + hh * 8];
#pragma unroll
            for (int q = 0; q < 4; q++) {
                int nt = w * 4 + q;
                bf16x8 b;
                if (PACKED) b = wp[(kt * 16 + nt) * 64 + lane];
                else        b = load_bfrag(wx2, 256, kt, nt, lane);
                acc[q] = __builtin_amdgcn_mfma_f32_16x16x32_bf16(a, b, acc[q], 0, 0, 0);
            }
        }
        // X2[m'][i=ntE][j=cl]; dest lane' = (j>>3)*16 + i, jj = j&7
#pragma unroll
        for (int q = 0; q < 4; q++) {
            int ntE = w * 4 + q;
            int lp  = (cl >> 3) * 16 + ntE;
            int jj  = cl & 7;
#pragma unroll
            for (int r = 0; r < 4; r++) {
                int m = hh * 4 + r;
                s_x2f[(m * 32 + lp) * 8 + jj] = f2bf(acc[q][r]);
            }
        }
    }
    __syncthreads();

    // ---- Phase F: fts_X via MFMA (zero-padded K=16) + depthwise via butterfly ----
    {
        const int cA = w * 16 + cl;          // channel 0..63  (h2 half)
        const int cB = 64 + w * 16 + cl;     // channel 64..127 (fts half)
        float wdA[16], wdB[16];
#pragma unroll
        for (int d = 0; d < 4; d++) {
            float4 va = *(const float4*)&wdw[cA * 64 + d * 16 + 4 * hh];
            wdA[d * 4 + 0] = va.x; wdA[d * 4 + 1] = va.y; wdA[d * 4 + 2] = va.z; wdA[d * 4 + 3] = va.w;
            float4 vb = *(const float4*)&wdw[cB * 64 + d * 16 + 4 * hh];
            wdB[d * 4 + 0] = vb.x; wdB[d * 4 + 1] = vb.y; wdB[d * 4 + 2] = vb.z; wdB[d * 4 + 3] = vb.w;
        }
        float4 bdA = *(const float4*)&bdw[cA * 4];
        float4 bdB = *(const float4*)&bdw[cB * 4];
        const float* ftsp = fts + (size_t)gp0 * 1024 + (w * 16 + cl);

        float f0[8], f1[8];
        auto LDF = [&](int m, float* f) {
            if (lane < 32) {
                const float* p = ftsp + (m * 16 + hh * 8) * 64;
#pragma unroll
                for (int j = 0; j < 8; j++) f[j] = p[j * 64];
            }
        };
        auto BODY = [&](int m, float* fc_, float* fn_) {
            if (m < 15) LDF(m + 1, fn_);
            bf16x8 a  = {};
            bf16x8 bh = {};
            if (lane < 32) {
                a  = *(const bf16x8*)&s_x2f[(m * 32 + lane) * 8];
                bh = *(const bf16x8*)&s_h2f[((m * 4 + w) * 32 + lane) * 8];
            }
            f32x4 accA = {0.f, 0.f, 0.f, 0.f};
            f32x4 accB = {0.f, 0.f, 0.f, 0.f};
            accA = __builtin_amdgcn_mfma_f32_16x16x32_bf16(a, bh, accA, 0, 0, 0);
            bf16x8 bf_ = {};
            if (lane < 32) {
                union { bf16x8 v; uint4 u; } ub;
                ub.u = make_uint4(pk2(fc_[0], fc_[1]), pk2(fc_[2], fc_[3]),
                                  pk2(fc_[4], fc_[5]), pk2(fc_[6], fc_[7]));
                bf_ = ub.v;
            }
            accB = __builtin_amdgcn_mfma_f32_16x16x32_bf16(a, bf_, accB, 0, 0, 0);
            // depthwise: rows i = 4*hh + r live in this lane; reduce across hh groups
            float oA[4], oB[4];
#pragma unroll
            for (int d = 0; d < 4; d++) {
                float sA = accA[0] * wdA[d * 4 + 0];
                sA = fmaf(accA[1], wdA[d * 4 + 1], sA);
                sA = fmaf(accA[2], wdA[d * 4 + 2], sA);
                sA = fmaf(accA[3], wdA[d * 4 + 3], sA);
                sA += __shfl_xor(sA, 16);
                sA += __shfl_xor(sA, 32);
                oA[d] = sA;
                float sB = accB[0] * wdB[d * 4 + 0];
                sB = fmaf(accB[1], wdB[d * 4 + 1], sB);
                sB = fmaf(accB[2], wdB[d * 4 + 2], sB);
                sB = fmaf(accB[3], wdB[d * 4 + 3], sB);
                sB += __shfl_xor(sB, 16);
                sB += __shfl_xor(sB, 32);
                oB[d] = sB;
            }
            if (hh == 0) {
                ushort4 va, vb;
                va.x = f2bf(oA[0] + bdA.x); va.y = f2bf(oA[1] + bdA.y);
                va.z = f2bf(oA[2] + bdA.z); va.w = f2bf(oA[3] + bdA.w);
                vb.x = f2bf(oB[0] + bdB.x); vb.y = f2bf(oB[1] + bdB.y);
                vb.z = f2bf(oB[2] + bdB.z); vb.w = f2bf(oB[3] + bdB.w);
                *(ushort4*)&s_dw[m * 520 + cA * 4] = va;
                *(ushort4*)&s_dw[m * 520 + cB * 4] = vb;
            }
        };
        LDF(0, f0);
#pragma unroll
        for (int mm = 0; mm < 8; mm++) {
            BODY(2 * mm + 0, f0, f1);
            BODY(2 * mm + 1, f1, f0);
        }
    }
    __syncthreads();

    // ---- Phase G: y = BN(elu(dw @ wpw + bpw)), MFMA M=16,N=128,K=512 ----
    {
        const bf16x8* wp = (const bf16x8*)wpack + 16896;  // wpw
        f32x4 acc[2];
#pragma unroll
        for (int q = 0; q < 2; q++) {
            float bv = bpw[(w * 2 + q) * 16 + cl];
            acc[q] = (f32x4){bv, bv, bv, bv};
        }
#pragma unroll
        for (int kt = 0; kt < 16; kt++) {
            bf16x8 a = *(const bf16x8*)&s_dw[cl * 520 + kt * 32 + hh * 8];
#pragma unroll
            for (int q = 0; q < 2; q++) {
                int nt = w * 2 + q;
                bf16x8 b;
                if (PACKED) b = wp[(kt * 8 + nt) * 64 + lane];
                else        b = load_bfrag(wpw, 128, kt, nt, lane);
                acc[q] = __builtin_amdgcn_mfma_f32_16x16x32_bf16(a, b, acc[q], 0, 0, 0);
            }
        }
#pragma unroll
        for (int q = 0; q < 2; q++) {
            int co = (w * 2 + q) * 16 + cl;
            float scale = bn_gamma[co] * rsqrtf(bn_var[co] + 1e-5f);
            float shift = bn_beta[co] - bn_mean[co] * scale;
#pragma unroll
            for (int r = 0; r < 4; r++) {
                int m = hh * 4 + r;
                out[(gp0 + m) * 128 + co] = fmaf(elu_f(acc[q][r]), scale, shift);
            }
        }
    }
}

extern "C" void kernel_launch(void* const* d_in, const int* in_sizes, int n_in,
                              void* d_out, int out_size, void* d_ws, size_t ws_size,
                              hipStream_t stream) {
    const float* rep_pt   = (const float*)d_in[0];
    const float* pts      = (const float*)d_in[1];
    const float* fts      = (const float*)d_in[2];
    const float* w1       = (const float*)d_in[3];
    const float* b1       = (const float*)d_in[4];
    const float* w2       = (const float*)d_in[5];
    const float* b2       = (const float*)d_in[6];
    const float* wc1      = (const float*)d_in[7];
    const float* bc1      = (const float*)d_in[8];
    const float* wx1      = (const float*)d_in[9];
    const float* bx1      = (const float*)d_in[10];
    const float* wx2      = (const float*)d_in[11];
    const float* bx2      = (const float*)d_in[12];
    const float* wdw      = (const float*)d_in[13];
    const float* bdw      = (const float*)d_in[14];
    const float* wpw      = (const float*)d_in[15];
    const float* bpw      = (const float*)d_in[16];
    const float* bn_gamma = (const float*)d_in[17];
    const float* bn_beta  = (const float*)d_in[18];
    const float* bn_mean  = (const float*)d_in[19];
    const float* bn_var   = (const float*)d_in[20];
    float* out = (float*)d_out;

    const bool packed = (d_ws != nullptr) && (ws_size >= (size_t)WS_NEEDED);
    unsigned short* wpack = (unsigned short*)d_ws;

    if (packed) {
        pack_weights<<<98, 256, 0, stream>>>(w2, wx1, wx2, wpw, wpack);
        xconv_main<true><<<NPTS / MPB, NTHR, 0, stream>>>(
            rep_pt, pts, fts, w1, b1, w2, b2, wc1, bc1, wx1, bx1, wx2, bx2,
            wdw, bdw, wpw, bpw, bn_gamma, bn_beta, bn_mean, bn_var, wpack, out);
    } else {
        xconv_main<false><<<NPTS / MPB, NTHR, 0, stream>>>(
            rep_pt, pts, fts, w1, b1, w2, b2, wc1, bc1, wx1, bx1, wx2, bx2,
            wdw, bdw, wpw, bpw, bn_gamma, bn_beta, bn_mean, bn_var, (const unsigned short*)nullptr, out);
    }
}